// Round 2
// baseline (108.318 us; speedup 1.0000x reference)
//
#include <hip/hip_runtime.h>

#define DIM   4096
#define BATCH 8192
// Two waves per row. Wave half h in {0,1} holds elements [2048h, 2048h+2048).
// Thread t holds e = 2048h + 256j + 4t + i  (j=0..7, i=0..3)  -> 8 float4 = 32 VGPRs.
// Layer L pairs e with e^(1<<L); coeff index = (4096 - (4096>>L)) + (e >> (L+1)).
//   L0..L1 : within float4 (i axis)            — register FMAs
//   L2..L7 : lane distance 1,2,4,8,16,32       — __shfl_xor
//   L8..L10: register index j distance 1,2,4   — register FMAs, wave-uniform coeffs
//   L11    : cross-wave (h axis)               — chunked LDS exchange (16 KB/block)

__device__ __forceinline__ void rot2(float& lo, float& hi, float a, float b) {
    float l = lo, h = hi;
    lo = fmaf(a, l,  b * h);   // top =  a*x0 + b*x1
    hi = fmaf(a, h, -b * l);   // bot = -b*x0 + a*x1
}

__device__ __forceinline__ void rot4(float4& lo, float4& hi, float a, float b) {
    rot2(lo.x, hi.x, a, b);
    rot2(lo.y, hi.y, a, b);
    rot2(lo.z, hi.z, a, b);
    rot2(lo.w, hi.w, a, b);
}

template<bool PACKED>
__device__ __forceinline__ float2 coef(const float* __restrict__ af,
                                       const float* __restrict__ bf,
                                       const float2* __restrict__ ab, int c) {
    if constexpr (PACKED) return ab[c];
    else                  return make_float2(af[c], bf[c]);
}

template<int M, int JSHIFT, int LANESHIFT, bool PACKED>
__device__ __forceinline__ void shuf_layer(float4* v, int lane, int base,
                                           const float* __restrict__ af,
                                           const float* __restrict__ bf,
                                           const float2* __restrict__ ab) {
    #pragma unroll
    for (int j = 0; j < 8; ++j) {
        const int c = base + (j << JSHIFT) + (lane >> LANESHIFT);
        float2 q = coef<PACKED>(af, bf, ab, c);
        const float sb = (lane & M) ? -q.y : q.y;   // top: +b*recv ; bot: -b*recv
        v[j].x = fmaf(q.x, v[j].x, sb * __shfl_xor(v[j].x, M, 64));
        v[j].y = fmaf(q.x, v[j].y, sb * __shfl_xor(v[j].y, M, 64));
        v[j].z = fmaf(q.x, v[j].z, sb * __shfl_xor(v[j].z, M, 64));
        v[j].w = fmaf(q.x, v[j].w, sb * __shfl_xor(v[j].w, M, 64));
    }
}

template<bool PACKED>
__global__ __launch_bounds__(256, 8)
void bfly_kernel(const float* __restrict__ x,
                 const float* __restrict__ af,
                 const float* __restrict__ bf,
                 const float2* __restrict__ ab,
                 float* __restrict__ out) {
    const int lane = threadIdx.x & 63;
    const int wid  = threadIdx.x >> 6;   // 0..3
    const int r    = wid >> 1;           // row-in-block: 0,1
    const int h    = wid & 1;            // row half: 0,1
    const size_t row = (size_t)blockIdx.x * 2 + r;

    const float4* __restrict__ xr = reinterpret_cast<const float4*>(x + row * DIM) + h * 512;
    float4* __restrict__ orow     = reinterpret_cast<float4*>(out + row * DIM) + h * 512;

    __shared__ float4 xch[2][2][4][64];  // [rowInBlock][half][jChunk][lane] = 16 KB

    float4 v[8];
    #pragma unroll
    for (int j = 0; j < 8; ++j) v[j] = xr[64 * j + lane];

    // ---- L0 (bs=1): pairs (x,y),(z,w); c0 = 1024h + 128j + 2*lane, and c0+1 ----
    #pragma unroll
    for (int j = 0; j < 8; ++j) {
        float a0, b0, a1, b1;
        if constexpr (PACKED) {
            float4 q = reinterpret_cast<const float4*>(ab)[h * 512 + 64 * j + lane]; // (a0,b0,a1,b1)
            a0 = q.x; b0 = q.y; a1 = q.z; b1 = q.w;
        } else {
            const int c = h * 1024 + 128 * j + 2 * lane;
            float2 aa = *reinterpret_cast<const float2*>(af + c);
            float2 bb = *reinterpret_cast<const float2*>(bf + c);
            a0 = aa.x; b0 = bb.x; a1 = aa.y; b1 = bb.y;
        }
        rot2(v[j].x, v[j].y, a0, b0);
        rot2(v[j].z, v[j].w, a1, b1);
    }

    // ---- L1 (bs=2): pairs (x,z),(y,w); c = 2048 + 512h + 64j + lane ----
    #pragma unroll
    for (int j = 0; j < 8; ++j) {
        float2 q = coef<PACKED>(af, bf, ab, 2048 + 512 * h + 64 * j + lane);
        rot2(v[j].x, v[j].z, q.x, q.y);
        rot2(v[j].y, v[j].w, q.x, q.y);
    }

    // ---- L2..L7: shuffle layers ----
    shuf_layer< 1, 5, 1, PACKED>(v, lane, 3072 + 256 * h, af, bf, ab);  // bs=4
    shuf_layer< 2, 4, 2, PACKED>(v, lane, 3584 + 128 * h, af, bf, ab);  // bs=8
    shuf_layer< 4, 3, 3, PACKED>(v, lane, 3840 +  64 * h, af, bf, ab);  // bs=16
    shuf_layer< 8, 2, 4, PACKED>(v, lane, 3968 +  32 * h, af, bf, ab);  // bs=32
    shuf_layer<16, 1, 5, PACKED>(v, lane, 4032 +  16 * h, af, bf, ab);  // bs=64
    shuf_layer<32, 0, 6, PACKED>(v, lane, 4064 +   8 * h, af, bf, ab);  // bs=128

    // ---- L8 (bs=256): pairs (2k, 2k+1); c = 4080 + 4h + k ----
    #pragma unroll
    for (int k = 0; k < 4; ++k) {
        float2 q = coef<PACKED>(af, bf, ab, 4080 + 4 * h + k);
        rot4(v[2 * k], v[2 * k + 1], q.x, q.y);
    }
    // ---- L9 (bs=512): pairs (j, j+2), j in {0,1,4,5}; c = 4088 + 2h + (j>>2) ----
    #pragma unroll
    for (int k = 0; k < 4; ++k) {
        const int j = ((k >> 1) << 2) | (k & 1);
        float2 q = coef<PACKED>(af, bf, ab, 4088 + 2 * h + (j >> 2));
        rot4(v[j], v[j + 2], q.x, q.y);
    }
    // ---- L10 (bs=1024): pairs (j, j+4), j=0..3; c = 4092 + h ----
    {
        float2 q = coef<PACKED>(af, bf, ab, 4092 + h);
        #pragma unroll
        for (int j = 0; j < 4; ++j) rot4(v[j], v[j + 4], q.x, q.y);
    }

    // ---- L11 (bs=2048): cross-wave via LDS, c = 4094 ----
    {
        float2 q = coef<PACKED>(af, bf, ab, 4094);
        const float sb = h ? -q.y : q.y;   // h=0 (top): a*own + b*partner ; h=1 (bot): a*own - b*partner

        #pragma unroll
        for (int j = 0; j < 4; ++j) xch[r][h][j][lane] = v[j];
        __syncthreads();
        #pragma unroll
        for (int j = 0; j < 4; ++j) {
            float4 p = xch[r][h ^ 1][j][lane];
            v[j].x = fmaf(q.x, v[j].x, sb * p.x);
            v[j].y = fmaf(q.x, v[j].y, sb * p.y);
            v[j].z = fmaf(q.x, v[j].z, sb * p.z);
            v[j].w = fmaf(q.x, v[j].w, sb * p.w);
        }
        __syncthreads();
        #pragma unroll
        for (int j = 4; j < 8; ++j) xch[r][h][j - 4][lane] = v[j];
        __syncthreads();
        #pragma unroll
        for (int j = 4; j < 8; ++j) {
            float4 p = xch[r][h ^ 1][j - 4][lane];
            v[j].x = fmaf(q.x, v[j].x, sb * p.x);
            v[j].y = fmaf(q.x, v[j].y, sb * p.y);
            v[j].z = fmaf(q.x, v[j].z, sb * p.z);
            v[j].w = fmaf(q.x, v[j].w, sb * p.w);
        }
    }

    #pragma unroll
    for (int j = 0; j < 8; ++j) orow[64 * j + lane] = v[j];
}

__global__ void pack_ab_kernel(const float* __restrict__ af,
                               const float* __restrict__ bf,
                               float2* __restrict__ ab) {
    int i = blockIdx.x * 256 + threadIdx.x;
    if (i < DIM - 1) ab[i] = make_float2(af[i], bf[i]);
}

extern "C" void kernel_launch(void* const* d_in, const int* in_sizes, int n_in,
                              void* d_out, int out_size, void* d_ws, size_t ws_size,
                              hipStream_t stream) {
    const float* x  = (const float*)d_in[0];
    const float* af = (const float*)d_in[1];
    const float* bf = (const float*)d_in[2];
    float* out      = (float*)d_out;

    const bool packed = (d_ws != nullptr) && (ws_size >= (size_t)(DIM - 1) * sizeof(float2));
    if (packed) {
        float2* ab = (float2*)d_ws;
        hipLaunchKernelGGL(pack_ab_kernel, dim3(16), dim3(256), 0, stream, af, bf, ab);
        hipLaunchKernelGGL((bfly_kernel<true>),  dim3(BATCH / 2), dim3(256), 0, stream,
                           x, af, bf, ab, out);
    } else {
        hipLaunchKernelGGL((bfly_kernel<false>), dim3(BATCH / 2), dim3(256), 0, stream,
                           x, af, bf, nullptr, out);
    }
}

// Round 3
// 58.648 us; speedup vs baseline: 1.8469x; 1.8469x over previous
//
#include <hip/hip_runtime.h>

#define DIM   4096
#define BATCH 8192
// One row per 256-thread block; wave q in {0..3} owns elements [1024q, 1024q+1024).
// Thread t (lane) holds e = 1024q + 256j + 4t + i  (j=0..3, i=0..3) -> 4 float4 = 16 VGPRs.
// Layer L pairs e with e^(1<<L); coeff index c = (4096 - (4096>>L)) + (e >> (L+1)).
//   L0..L1 : within float4 (i axis)           — register FMAs
//   L2..L7 : lane distance 1,2,4,8,16,32      — __shfl_xor
//   L8..L9 : register index j distance 1,2    — register FMAs
//   L10..L11: cross-wave (q axis)             — LDS exchange (16 KB/block, 3 barriers)
// VGPR budget: 16 data + ~32 overhead, capped at 64 by __launch_bounds__(256,8)
// (R1 lesson: a cap BELOW the data set forces spill — 84 MB extra HBM writes).

__device__ __forceinline__ void rot2(float& lo, float& hi, float a, float b) {
    float l = lo, h = hi;
    lo = fmaf(a, l,  b * h);   // top =  a*x0 + b*x1
    hi = fmaf(a, h, -b * l);   // bot = -b*x0 + a*x1
}

template<bool PACKED>
__device__ __forceinline__ float2 coef(const float* __restrict__ af,
                                       const float* __restrict__ bf,
                                       const float2* __restrict__ ab, int c) {
    if constexpr (PACKED) return ab[c];
    else                  return make_float2(af[c], bf[c]);
}

// Shuffle layer: M = lane-xor distance, JSH = j coeff shift, LSH = lane coeff shift.
template<int M, int JSH, int LSH, bool PACKED>
__device__ __forceinline__ void shuf_layer(float4* v, int lane, int base,
                                           const float* __restrict__ af,
                                           const float* __restrict__ bf,
                                           const float2* __restrict__ ab) {
    #pragma unroll
    for (int j = 0; j < 4; ++j) {
        const int c = base + (j << JSH) + (lane >> LSH);
        float2 q = coef<PACKED>(af, bf, ab, c);
        const float sb = (lane & M) ? -q.y : q.y;   // top: +b*partner ; bot: -b*partner
        v[j].x = fmaf(q.x, v[j].x, sb * __shfl_xor(v[j].x, M, 64));
        v[j].y = fmaf(q.x, v[j].y, sb * __shfl_xor(v[j].y, M, 64));
        v[j].z = fmaf(q.x, v[j].z, sb * __shfl_xor(v[j].z, M, 64));
        v[j].w = fmaf(q.x, v[j].w, sb * __shfl_xor(v[j].w, M, 64));
    }
}

template<bool PACKED>
__global__ __launch_bounds__(256, 8)
void bfly_kernel(const float* __restrict__ x,
                 const float* __restrict__ af,
                 const float* __restrict__ bf,
                 const float2* __restrict__ ab,
                 float* __restrict__ out) {
    const int lane = threadIdx.x & 63;
    const int q    = threadIdx.x >> 6;     // wave index = row quarter
    const size_t row = blockIdx.x;

    const float4* __restrict__ xr = reinterpret_cast<const float4*>(x + row * DIM) + q * 256;
    float4* __restrict__ orow     = reinterpret_cast<float4*>(out + row * DIM) + q * 256;

    __shared__ float4 xch[4][4][64];   // [wave][j][lane] = 16 KB

    float4 v[4];
    #pragma unroll
    for (int j = 0; j < 4; ++j) v[j] = xr[64 * j + lane];

    // ---- L0 (bs=1): pairs (x,y),(z,w); c0 = 512q + 128j + 2*lane, c0+1 ----
    #pragma unroll
    for (int j = 0; j < 4; ++j) {
        float a0, b0, a1, b1;
        if constexpr (PACKED) {
            float4 p = reinterpret_cast<const float4*>(ab)[q * 256 + 64 * j + lane]; // (a0,b0,a1,b1)
            a0 = p.x; b0 = p.y; a1 = p.z; b1 = p.w;
        } else {
            const int c = 512 * q + 128 * j + 2 * lane;
            float2 aa = *reinterpret_cast<const float2*>(af + c);
            float2 bb = *reinterpret_cast<const float2*>(bf + c);
            a0 = aa.x; b0 = bb.x; a1 = aa.y; b1 = bb.y;
        }
        rot2(v[j].x, v[j].y, a0, b0);
        rot2(v[j].z, v[j].w, a1, b1);
    }

    // ---- L1 (bs=2): pairs (x,z),(y,w); c = 2048 + 256q + 64j + lane ----
    #pragma unroll
    for (int j = 0; j < 4; ++j) {
        float2 p = coef<PACKED>(af, bf, ab, 2048 + 256 * q + 64 * j + lane);
        rot2(v[j].x, v[j].z, p.x, p.y);
        rot2(v[j].y, v[j].w, p.x, p.y);
    }

    // ---- L2..L7: shuffle layers ----
    shuf_layer< 1, 5, 1, PACKED>(v, lane, 3072 + 128 * q, af, bf, ab);  // bs=4
    shuf_layer< 2, 4, 2, PACKED>(v, lane, 3584 +  64 * q, af, bf, ab);  // bs=8
    shuf_layer< 4, 3, 3, PACKED>(v, lane, 3840 +  32 * q, af, bf, ab);  // bs=16
    shuf_layer< 8, 2, 4, PACKED>(v, lane, 3968 +  16 * q, af, bf, ab);  // bs=32
    shuf_layer<16, 1, 5, PACKED>(v, lane, 4032 +   8 * q, af, bf, ab);  // bs=64
    shuf_layer<32, 0, 6, PACKED>(v, lane, 4064 +   4 * q, af, bf, ab);  // bs=128 (lane>>6 == 0)

    // ---- L8 (bs=256): pairs (0,1),(2,3); c = 4080 + 2q + (j>>1) ----
    #pragma unroll
    for (int k = 0; k < 2; ++k) {
        float2 p = coef<PACKED>(af, bf, ab, 4080 + 2 * q + k);
        rot2(v[2*k].x, v[2*k+1].x, p.x, p.y);
        rot2(v[2*k].y, v[2*k+1].y, p.x, p.y);
        rot2(v[2*k].z, v[2*k+1].z, p.x, p.y);
        rot2(v[2*k].w, v[2*k+1].w, p.x, p.y);
    }
    // ---- L9 (bs=512): pairs (0,2),(1,3); c = 4088 + q ----
    {
        float2 p = coef<PACKED>(af, bf, ab, 4088 + q);
        #pragma unroll
        for (int j = 0; j < 2; ++j) {
            rot2(v[j].x, v[j+2].x, p.x, p.y);
            rot2(v[j].y, v[j+2].y, p.x, p.y);
            rot2(v[j].z, v[j+2].z, p.x, p.y);
            rot2(v[j].w, v[j+2].w, p.x, p.y);
        }
    }

    // ---- L10 (bs=1024): partner wave q^1; c = 4092 + (q>>1) ----
    {
        float2 p = coef<PACKED>(af, bf, ab, 4092 + (q >> 1));
        const float sb = (q & 1) ? -p.y : p.y;
        #pragma unroll
        for (int j = 0; j < 4; ++j) xch[q][j][lane] = v[j];
        __syncthreads();
        #pragma unroll
        for (int j = 0; j < 4; ++j) {
            float4 w = xch[q ^ 1][j][lane];
            v[j].x = fmaf(p.x, v[j].x, sb * w.x);
            v[j].y = fmaf(p.x, v[j].y, sb * w.y);
            v[j].z = fmaf(p.x, v[j].z, sb * w.z);
            v[j].w = fmaf(p.x, v[j].w, sb * w.w);
        }
    }
    __syncthreads();   // protect xch against write-after-read
    // ---- L11 (bs=2048): partner wave q^2; c = 4094 ----
    {
        float2 p = coef<PACKED>(af, bf, ab, 4094);
        const float sb = (q & 2) ? -p.y : p.y;
        #pragma unroll
        for (int j = 0; j < 4; ++j) xch[q][j][lane] = v[j];
        __syncthreads();
        #pragma unroll
        for (int j = 0; j < 4; ++j) {
            float4 w = xch[q ^ 2][j][lane];
            v[j].x = fmaf(p.x, v[j].x, sb * w.x);
            v[j].y = fmaf(p.x, v[j].y, sb * w.y);
            v[j].z = fmaf(p.x, v[j].z, sb * w.z);
            v[j].w = fmaf(p.x, v[j].w, sb * w.w);
        }
    }

    #pragma unroll
    for (int j = 0; j < 4; ++j) orow[64 * j + lane] = v[j];
}

__global__ void pack_ab_kernel(const float* __restrict__ af,
                               const float* __restrict__ bf,
                               float2* __restrict__ ab) {
    int i = blockIdx.x * 256 + threadIdx.x;
    if (i < DIM - 1) ab[i] = make_float2(af[i], bf[i]);
}

extern "C" void kernel_launch(void* const* d_in, const int* in_sizes, int n_in,
                              void* d_out, int out_size, void* d_ws, size_t ws_size,
                              hipStream_t stream) {
    const float* x  = (const float*)d_in[0];
    const float* af = (const float*)d_in[1];
    const float* bf = (const float*)d_in[2];
    float* out      = (float*)d_out;

    const bool packed = (d_ws != nullptr) && (ws_size >= (size_t)(DIM - 1) * sizeof(float2));
    if (packed) {
        float2* ab = (float2*)d_ws;
        hipLaunchKernelGGL(pack_ab_kernel, dim3(16), dim3(256), 0, stream, af, bf, ab);
        hipLaunchKernelGGL((bfly_kernel<true>),  dim3(BATCH), dim3(256), 0, stream,
                           x, af, bf, ab, out);
    } else {
        hipLaunchKernelGGL((bfly_kernel<false>), dim3(BATCH), dim3(256), 0, stream,
                           x, af, bf, nullptr, out);
    }
}